// Round 7
// baseline (254.160 us; speedup 1.0000x reference)
//
#include <hip/hip_runtime.h>

#define NA    3
#define CP5   85
#define NC    80
#define NB    64
#define NG    52
#define GG    (NG * NG)        // 2704
#define NCELL (NB * GG)        // 173056
#define PLANE GG
#define CELLW (1.0f / 52.0f)

#define MBLOCKS (NCELL / 256)  // 676 exact

// ws layout (all cross-block traffic via AGENT-scope atomics; ws starts 0xAA-poisoned):
//   @0     float obj_part[676]
//   @2816  float noobj_part[676]
//   @5632  float cnt_part[676]
//   @8448  unsigned flags[676]     (sentinel 1u written each run; 0xAAAAAAAA != 1)
#define OFF_NO   2816
#define OFF_CNT  5632
#define OFF_FLAG 8448

__global__ __launch_bounds__(256) void yolo_fused(const float* __restrict__ pred,
                                                  const float* __restrict__ targ,
                                                  float* __restrict__ obj_part,
                                                  float* __restrict__ noobj_part,
                                                  float* __restrict__ cnt_part,
                                                  unsigned* __restrict__ flags,
                                                  float* __restrict__ out) {
    __shared__ unsigned short lst[256];
    __shared__ int   wcnt[4];
    __shared__ float wno[4];
    __shared__ float wobj[4];

    int tid  = threadIdx.x;
    int lane = tid & 63;
    int w    = tid >> 6;

    // ---- per-cell noobj + obj detection (grid exact, no bounds check)
    int n0 = blockIdx.x * 256 + tid;
    int b0 = n0 / GG, g0 = n0 - b0 * GG;
    const float* tb0 = targ + (size_t)b0 * 6 * PLANE + g0;
    float tobj = tb0[4 * PLANE];
    bool isobj = (tobj == 1.0f);
    float s_noobj = 0.f;
    if (!isobj) {
        const float* pb0 = pred + (size_t)b0 * (NA * CP5) * PLANE + g0;
        float c0 = pb0[(0 * CP5 + 4) * PLANE];
        float c1 = pb0[(1 * CP5 + 4) * PLANE];
        float c2 = pb0[(2 * CP5 + 4) * PLANE];
        // log(a)+log(b)+log(c) = log(abc); product in (1e-6, 0.97): one logf not three
        s_noobj = -logf((1.f - c0) * (1.f - c1) * (1.f - c2));
    }
    unsigned long long ball = __ballot(isobj);
    int within = __popcll(ball & ((1ull << lane) - 1ull));
    #pragma unroll
    for (int o = 32; o > 0; o >>= 1) s_noobj += __shfl_down(s_noobj, o);
    if (lane == 0) { wcnt[w] = (int)__popcll(ball); wno[w] = s_noobj; }
    __syncthreads();
    int c0n = wcnt[0], c1n = wcnt[1], c2n = wcnt[2], c3n = wcnt[3];
    int wbase = (w > 0 ? c0n : 0) + (w > 1 ? c1n : 0) + (w > 2 ? c2n : 0);
    int tot = c0n + c1n + c2n + c3n;          // <= 256 == lst capacity
    if (isobj) lst[wbase + within] = (unsigned short)tid;
    __syncthreads();

    // ---- obj cells: 4 waves stride the block-local list (validated wave-coop body)
    float a_sum = 0.f;   // lane 0: 0.5*coord + obj + cls
    for (int j = w; j < tot; j += 4) {
        int n = blockIdx.x * 256 + (int)lst[j];   // uniform LDS read: broadcast
        int b   = n / GG;
        int g   = n - b * GG;
        int row = g / NG;
        int col = g - row * NG;
        const float* pb = pred + (size_t)b * (NA * CP5) * PLANE + g;
        const float* tb = targ + (size_t)b * 6 * PLANE + g;

        float tv = (lane < 6) ? tb[(size_t)lane * PLANE] : 0.f;
        float av = 0.f;
        if (lane < 15) {
            int a = lane / 5, k = lane - 5 * a;
            av = pb[((size_t)(a * CP5 + k)) * PLANE];
        }
        float tx = __shfl(tv, 0), ty = __shfl(tv, 1);
        float tw = __shfl(tv, 2), th = __shfl(tv, 3);
        int tcls = (int)__shfl(tv, 5);

        float colf = (float)col * CELLW, rowf = (float)row * CELLW;
        float bx1 = tx - tw * 0.5f, by1 = ty - th * 0.5f;
        float bx2 = tx + tw * 0.5f, by2 = ty + th * 0.5f;
        float area_b = (bx2 - bx1) * (by2 - by1);

        float best_iou = -1e30f;
        int best = 0;
        float bpx = 0, bpy = 0, bpw = 0, bph = 0, bpc = 0;
        #pragma unroll
        for (int a = 0; a < NA; ++a) {
            float px = __shfl(av, 5 * a + 0) + colf;
            float py = __shfl(av, 5 * a + 1) + rowf;
            float pw = __shfl(av, 5 * a + 2);
            float ph = __shfl(av, 5 * a + 3);
            float pc = __shfl(av, 5 * a + 4);
            float ax1 = px - pw * 0.5f, ay1 = py - ph * 0.5f;
            float ax2 = px + pw * 0.5f, ay2 = py + ph * 0.5f;
            float iw = fmaxf(fminf(ax2, bx2) - fmaxf(ax1, bx1), 0.f);
            float ih = fmaxf(fminf(ay2, by2) - fmaxf(ay1, by1), 0.f);
            float inter  = iw * ih;
            float area_a = (ax2 - ax1) * (ay2 - ay1);
            float iou    = inter / (area_a + area_b - inter);
            if (iou > best_iou) {   // strict > = first-occurrence argmax (matches jnp.argmax)
                best_iou = iou; best = a;
                bpx = px; bpy = py; bpw = pw; bph = ph; bpc = pc;
            }
        }

        const float* cls = pb + ((size_t)(best * CP5 + 5)) * PLANE;
        float x1 = cls[(size_t)lane * PLANE];
        float x2 = (lane < 16) ? cls[(size_t)(64 + lane) * PLANE] : 0.f;
        // pred in (0.01,0.99) => sum(exp(x)) <= 80*e, safe without max-shift
        float psum = __expf(x1) + ((lane < 16) ? __expf(x2) : 0.f);
        #pragma unroll
        for (int o = 32; o > 0; o >>= 1) psum += __shfl_down(psum, o);
        float v1 = __shfl(x1, tcls & 63);
        float v2 = __shfl(x2, tcls & 63);
        float x_cls = (tcls < 64) ? v1 : v2;

        if (lane == 0) {
            float dx = bpx - tx, dy = bpy - ty;
            float dw = sqrtf(bpw) - sqrtf(tw);
            float dh = sqrtf(bph) - sqrtf(th);
            float coord = dx * dx + dy * dy + dw * dw + dh * dh;
            a_sum += 0.5f * coord + (-logf(bpc)) + (logf(psum) - x_cls);
        }
    }

    if (lane == 0) wobj[w] = a_sum;
    __syncthreads();

    // ---- publish partials + flag (AGENT scope: cross-XCD coherent point)
    if (tid == 0) {
        __hip_atomic_store(&obj_part[blockIdx.x],   wobj[0] + wobj[1] + wobj[2] + wobj[3],
                           __ATOMIC_RELAXED, __HIP_MEMORY_SCOPE_AGENT);
        __hip_atomic_store(&noobj_part[blockIdx.x], wno[0] + wno[1] + wno[2] + wno[3],
                           __ATOMIC_RELAXED, __HIP_MEMORY_SCOPE_AGENT);
        __hip_atomic_store(&cnt_part[blockIdx.x],   (float)tot,   // exact: int <= 256
                           __ATOMIC_RELAXED, __HIP_MEMORY_SCOPE_AGENT);
        __hip_atomic_store(&flags[blockIdx.x], 1u,
                           __ATOMIC_RELEASE, __HIP_MEMORY_SCOPE_AGENT);
    }

    // ---- block 0: wait for all flags, then reduce. No other block depends on
    // block 0, so forward progress is unconditional (no cooperative launch needed).
    if (blockIdx.x == 0) {
        for (int i = tid; i < MBLOCKS; i += 256) {
            while (__hip_atomic_load(&flags[i], __ATOMIC_ACQUIRE, __HIP_MEMORY_SCOPE_AGENT) != 1u) {
                __builtin_amdgcn_s_sleep(2);
            }
        }
        __syncthreads();
        __shared__ float ao[4], an[4], ac[4];
        float s_obj = 0.f, s_no = 0.f, s_c = 0.f;
        for (int i = tid; i < MBLOCKS; i += 256) {
            s_obj += __hip_atomic_load(&obj_part[i],   __ATOMIC_RELAXED, __HIP_MEMORY_SCOPE_AGENT);
            s_no  += __hip_atomic_load(&noobj_part[i], __ATOMIC_RELAXED, __HIP_MEMORY_SCOPE_AGENT);
            s_c   += __hip_atomic_load(&cnt_part[i],   __ATOMIC_RELAXED, __HIP_MEMORY_SCOPE_AGENT);
        }
        #pragma unroll
        for (int o = 32; o > 0; o >>= 1) {
            s_obj += __shfl_down(s_obj, o);
            s_no  += __shfl_down(s_no, o);
            s_c   += __shfl_down(s_c, o);
        }
        if (lane == 0) { ao[w] = s_obj; an[w] = s_no; ac[w] = s_c; }
        __syncthreads();
        if (tid == 0) {
            float obj   = ao[0] + ao[1] + ao[2] + ao[3];
            float no    = an[0] + an[1] + an[2] + an[3];
            float n_obj = ac[0] + ac[1] + ac[2] + ac[3];
            out[0] = obj / n_obj + no / (3.f * ((float)NCELL - n_obj));
        }
    }
}

extern "C" void kernel_launch(void* const* d_in, const int* in_sizes, int n_in,
                              void* d_out, int out_size, void* d_ws, size_t ws_size,
                              hipStream_t stream) {
    const float* pred = (const float*)d_in[0];
    const float* targ = (const float*)d_in[1];
    float* out = (float*)d_out;

    float*    obj_part   = (float*)d_ws;
    float*    noobj_part = (float*)((char*)d_ws + OFF_NO);
    float*    cnt_part   = (float*)((char*)d_ws + OFF_CNT);
    unsigned* flags      = (unsigned*)((char*)d_ws + OFF_FLAG);

    // single dispatch: partials published via agent-scope atomics, block 0 reduces.
    // No memset needed: flags use a written sentinel (1u), never an assumed-zero.
    yolo_fused<<<dim3(MBLOCKS), dim3(256), 0, stream>>>(pred, targ, obj_part, noobj_part,
                                                        cnt_part, flags, out);
}